// Round 17
// baseline (260.546 us; speedup 1.0000x reference)
//
#include <hip/hip_runtime.h>
#include <hip/hip_bf16.h>
#include <stdint.h>

#define B_    2
#define S_    4096
#define DM_   2048
#define H_    16
#define D_    128
#define M_TOT (B_ * S_)     // 8192
#define N_TOT (3 * DM_)     // 6144
#define K_TOT DM_           // 2048

typedef __attribute__((ext_vector_type(8))) short  short8;
typedef __attribute__((ext_vector_type(4))) float  f32x4;
typedef unsigned short ushort_t;

__device__ __forceinline__ unsigned short f2bf(float f) {
    union { float f; unsigned u; } u; u.f = f;
    unsigned r = u.u + 0x7fffu + ((u.u >> 16) & 1u);
    return (unsigned short)(r >> 16);
}
__device__ __forceinline__ float bf2f(unsigned short s) {
    union { unsigned u; float f; } u; u.u = ((unsigned)s) << 16;
    return u.f;
}

__device__ __forceinline__ void gload_lds16(const void* g, void* l) {
    __builtin_amdgcn_global_load_lds(
        (const __attribute__((address_space(1))) void*)g,
        (__attribute__((address_space(3))) void*)l,
        16, 0, 0);
}

// ------------- fused cast fp32->bf16: x,Wq,Wk,Wv -> one contiguous dst -----
__global__ void cast_all(const float* __restrict__ x,  const float* __restrict__ Wq,
                         const float* __restrict__ Wk, const float* __restrict__ Wv,
                         unsigned short* __restrict__ dst) {
    const int NX = (M_TOT * K_TOT) / 4;   // 4,194,304 float4s
    const int NW = (DM_ * DM_) / 4;       // 1,048,576
    const int NT = NX + 3 * NW;           // 7,340,032
    int i = blockIdx.x * blockDim.x + threadIdx.x;
    const int stride = gridDim.x * blockDim.x;
    for (; i < NT; i += stride) {
        const float4* src; int j;
        if (i < NX)              { src = (const float4*)x;  j = i; }
        else if (i < NX + NW)    { src = (const float4*)Wq; j = i - NX; }
        else if (i < NX + 2*NW)  { src = (const float4*)Wk; j = i - NX - NW; }
        else                     { src = (const float4*)Wv; j = i - NX - 2*NW; }
        float4 v = src[j];
        ushort4 o;
        o.x = f2bf(v.x); o.y = f2bf(v.y); o.z = f2bf(v.z); o.w = f2bf(v.w);
        ((ushort4*)dst)[i] = o;
    }
}

// ------- QKV GEMM: 256x256, 16x16 MFMA, BKT=32, 64 KiB LDS -> 2 blocks/CU --
// C[M][N] = A[M][K] * B[N][K]^T (+bias), bf16 in, bf16 out.
// 512 thr = 8 waves (2M x 4N); per-wave output 128x64 (8x4 frags of 16x16).
// WHY: R9-R16 all plateau 51-55% MfmaUtil because 128 KiB LDS allows only
// ONE block/CU (LDS_Block_Size=131072, 160 KiB/CU) — the only overlap
// resource is 2 barrier-synced waves of the SAME block. Halving to
// 2 x (A[256][32]+B[256][32]) = 64 KiB gives 2 co-resident blocks/CU:
// block A's barrier/drain windows fill with block B's MFMAs (m97/m114
// mechanism). Registers don't cap occupancy (2048/SIMD pool).
// Per K-tile (BKT=32): 2 phases x 16 MFMA, reads 8/4, 4 gloads/wave.
// Ownership staging: wave w owns A,B subtiles {w, w+8} (1 KiB each).
//   w0-3's A subtiles = a1-region (frags 0-3); w4-7's = a2-region.
//   P1: rd a1(4),b(4) | w4-7: stage a2(T+1)->buf[T+1] | 16 mfma | VM4 | BAR
//   P2: rd a2(4)      | w0-3: stage a1(T+2)->buf[T]; all: B(T+2) | 16 mfma | VM4 | BAR
// Hazard ledger (verified per wave-role): every staged region's last read
// precedes a barrier that precedes the stage-issue; uniform VM4 at each
// phase end drains only loads >=2 phases (~1200cy) old -> no HBM stalls
// (single ~300cy exception at final VM0, once).

#define BKT   32
#define NKT   (K_TOT / BKT)   // 64 K-tiles
#define ABUF  8192            // ushort offset of B region within a buffer
#define BUF1  16384           // ushort offset of buffer 1

#define PB() do { asm volatile("" ::: "memory");                               \
                  __builtin_amdgcn_s_barrier();                                \
                  asm volatile("" ::: "memory"); } while (0)
#define VM4()   asm volatile("s_waitcnt vmcnt(4)" ::: "memory")
#define VM0()   asm volatile("s_waitcnt vmcnt(0)" ::: "memory")
#define SP1()   __builtin_amdgcn_s_setprio(1)
#define SP0()   __builtin_amdgcn_s_setprio(0)
#define NOSTAGE do {} while (0)
#define NOVM    do {} while (0)

// stage one 16x32 LDS subtile (1 gload_lds) of A or B at k-offset K0
#define STAGE_A(BO, K0, S) \
    gload_lds16(aStage + (size_t)(S) * (16 * K_TOT) + (K0), &lds[(BO) + (S) * 512])
#define STAGE_B(BO, K0, S) \
    gload_lds16(bStage + (size_t)(S) * (16 * K_TOT) + (K0), &lds[(BO) + ABUF + (S) * 512])

#define READ_A(DST, I0, BO) do { _Pragma("unroll")                              \
    for (int i = 0; i < 4; ++i)                                                 \
        DST[i] = *(const short8*)&lds[(BO) + (wm * 8 + (I0) + i) * 512 + innerRd]; \
    } while (0)

#define READ_Bv(BO) do { _Pragma("unroll")                                      \
    for (int n = 0; n < 4; ++n)                                                 \
        b[n] = *(const short8*)&lds[(BO) + ABUF + (wn * 4 + n) * 512 + innerRd]; \
    } while (0)

// 16 MFMA, every acc element touched once (16 independent chains)
#define MQ16(AR, I0) do { _Pragma("unroll")                                     \
    for (int i = 0; i < 4; ++i) { _Pragma("unroll")                             \
    for (int n = 0; n < 4; ++n)                                                 \
        acc[(I0) + i][n] = __builtin_amdgcn_mfma_f32_16x16x32_bf16(             \
            AR[i], b[n], acc[(I0) + i][n], 0, 0, 0);                            \
    } } while (0)

#define KTILE(BO, S1, S2, VM1, VM2) do {                                        \
    /* P1 */ READ_A(a1, 0, BO); READ_Bv(BO); S1;                                \
    SP1(); MQ16(a1, 0); SP0(); VM1; PB();                                       \
    /* P2 */ READ_A(a2, 4, BO); S2;                                             \
    SP1(); MQ16(a2, 4); SP0(); VM2; PB();                                       \
} while (0)

__global__ __launch_bounds__(512, 2) void gemm_qkv(
    const ushort_t* __restrict__ A,   // [M_TOT][K_TOT] bf16
    const ushort_t* __restrict__ Bm,  // [N_TOT][K_TOT] bf16 (Wq;Wk;Wv)
    const float* __restrict__ bq, const float* __restrict__ bk,
    const float* __restrict__ bv,
    ushort_t* __restrict__ C)         // [M_TOT][N_TOT] bf16
{
    __shared__ __align__(16) ushort_t lds[32768];   // 64 KiB -> 2 blocks/CU

    // XCD-aware bijective swizzle (768 % 8 == 0)
    const int nwg = gridDim.x;                  // 768
    const int cpx = nwg >> 3;                   // 96
    const int bid = blockIdx.x;
    const int swz = (bid & 7) * cpx + (bid >> 3);
    const int ntile = N_TOT / 256;              // 24
    const int tm = swz / ntile;
    const int tn = swz % ntile;
    const int tmRow = tm * 256, tnRow = tn * 256;

    const int tid  = threadIdx.x;
    const int w    = tid >> 6;
    const int lane = tid & 63;
    const int wm   = w >> 2, wn = w & 3;        // 2 x 4 wave grid
    const bool wHi = (w >= 4);                  // owns a2-region A subtiles

    // staging source (inverse-swizzle): lane L -> row L>>2, col ((L&3)*8)^((L>>5)<<4)
    const int rL     = lane >> 2;
    const int cSwzSt = ((lane & 3) * 8) ^ (((lane >> 5) & 1) << 4);
    const ushort_t* aStage = A  + (size_t)(tmRow + rL) * K_TOT + cSwzSt;
    const ushort_t* bStage = Bm + (size_t)(tnRow + rL) * K_TOT + cSwzSt;

    // ds_read fragment offset within a 16x32 subtile (st_16x32 swizzled):
    // row = lane&15, k0 = (lane>>4)*8 — the measured-clean 16x16 pattern
    const int rA      = lane & 15;
    const int innerRd = (rA * 32 + (lane >> 4) * 8) ^ (((rA >> 3) & 1) << 4);

    f32x4  acc[8][4] = {};
    short8 a1[4], a2[4], b[4];

    // prologue: T0 full -> buf0; T1's a1-region + B -> buf1 (a2(T1) at T0.P1).
    STAGE_A(0, 0, w); STAGE_A(0, 0, w + 8);
    STAGE_B(0, 0, w); STAGE_B(0, 0, w + 8);
    if (!wHi) { STAGE_A(BUF1, BKT, w); STAGE_A(BUF1, BKT, w + 8); }
    STAGE_B(BUF1, BKT, w); STAGE_B(BUF1, BKT, w + 8);
    VM0();
    PB();

    // steady loop: tiles 0..61 (31 iters); all 64 tiles' staging covered
    for (int kt = 0; kt < NKT - 2; kt += 2) {
        KTILE(0,
              { if (wHi) { STAGE_A(BUF1, (size_t)(kt + 1) * BKT, w);
                           STAGE_A(BUF1, (size_t)(kt + 1) * BKT, w + 8); } },
              { if (!wHi) { STAGE_A(0, (size_t)(kt + 2) * BKT, w);
                            STAGE_A(0, (size_t)(kt + 2) * BKT, w + 8); }
                STAGE_B(0, (size_t)(kt + 2) * BKT, w);
                STAGE_B(0, (size_t)(kt + 2) * BKT, w + 8); },
              VM4(), VM4());
        KTILE(BUF1,
              { if (wHi) { STAGE_A(0, (size_t)(kt + 2) * BKT, w);
                           STAGE_A(0, (size_t)(kt + 2) * BKT, w + 8); } },
              { if (!wHi) { STAGE_A(BUF1, (size_t)(kt + 3) * BKT, w);
                            STAGE_A(BUF1, (size_t)(kt + 3) * BKT, w + 8); }
                STAGE_B(BUF1, (size_t)(kt + 3) * BKT, w);
                STAGE_B(BUF1, (size_t)(kt + 3) * BKT, w + 8); },
              VM4(), VM4());
    }
    // tile 62 (buf0): P1 stages a2(63)->buf1; VM0 at end (one ~300cy stall)
    KTILE(0,
          { if (wHi) { STAGE_A(BUF1, (size_t)(NKT - 1) * BKT, w);
                       STAGE_A(BUF1, (size_t)(NKT - 1) * BKT, w + 8); } },
          NOSTAGE,
          VM4(), VM0());
    // tile 63 (buf1): pure drain
    KTILE(BUF1, NOSTAGE, NOSTAGE, NOVM, NOVM);

    // ---- epilogue: repack through LDS for coalesced 16B stores ----
    {
        ushort_t* ldsW = &lds[w * 1152];        // 16 rows x stride 72
        const int colBase = tnRow + wn * 64;
        const float* bias = (colBase < 2048) ? bq : (colBase < 4096) ? bk : bv;
        const int rowBase = tmRow + wm * 128;
        float bval[4];
#pragma unroll
        for (int n = 0; n < 4; ++n)
            bval[n] = bias[(colBase + n * 16 + (lane & 15)) & 2047];
#pragma unroll
        for (int i = 0; i < 8; ++i) {
#pragma unroll
            for (int n = 0; n < 4; ++n)
#pragma unroll
                for (int r = 0; r < 4; ++r)
                    ldsW[((lane >> 4) * 4 + r) * 72 + n * 16 + (lane & 15)] =
                        f2bf(acc[i][n][r] + bval[n]);
            asm volatile("s_waitcnt lgkmcnt(0)" ::: "memory");  // writes -> readable
#pragma unroll
            for (int half = 0; half < 2; ++half) {
                const int row = half * 8 + (lane >> 3);
                short8 v = *(const short8*)&ldsW[row * 72 + (lane & 7) * 8];
                *(short8*)&C[(size_t)(rowBase + i * 16 + row) * N_TOT +
                             colBase + (lane & 7) * 8] = v;
            }
            asm volatile("s_waitcnt lgkmcnt(0)" ::: "memory");  // reads done before next i
        }
    }
}

// ---------------- per-position heads-attention ----------------
#define LSTR 132   // padded fp32 row stride (breaks stride-128 bank conflicts)

__global__ __launch_bounds__(256) void attn_kernel(
    const ushort_t* __restrict__ QKV,  // [M_TOT][N_TOT] bf16
    float* __restrict__ out)           // [B][S][DM] fp32, scattered layout
{
    __shared__ __align__(16) float Qs[H_ * LSTR];
    __shared__ __align__(16) float Ks[H_ * LSTR];
    __shared__ __align__(16) float Vs[H_ * LSTR];

    const int pos = blockIdx.x;
    const int b   = pos >> 12;
    const int s   = pos & 4095;
    const int tid = threadIdx.x;
    const int lane = tid & 63;
    const ushort_t* row = QKV + (size_t)pos * N_TOT;

    {
        const int r  = tid >> 4;
        const int d0 = (tid & 15) * 8;
        short8 q = *(const short8*)(row +        r * 128 + d0);
        short8 k = *(const short8*)(row + 2048 + r * 128 + d0);
        short8 v = *(const short8*)(row + 4096 + r * 128 + d0);
#pragma unroll
        for (int j = 0; j < 8; ++j) {
            Qs[r * LSTR + d0 + j] = bf2f((unsigned short)q[j]);
            Ks[r * LSTR + d0 + j] = bf2f((unsigned short)k[j]);
            Vs[r * LSTR + d0 + j] = bf2f((unsigned short)v[j]);
        }
    }
    __syncthreads();

    const int h = tid >> 4;
    const int t = tid & 15;
    float sc = 0.f;
    {
        const float* qp = &Qs[h * LSTR];
        const float* kp = &Ks[t * LSTR];
#pragma unroll
        for (int d = 0; d < 128; d += 4) {
            float4 qv = *(const float4*)(qp + d);
            float4 kv = *(const float4*)(kp + d);
            sc += qv.x * kv.x + qv.y * kv.y + qv.z * kv.z + qv.w * kv.w;
        }
    }
    sc *= 0.08838834764831845f;   // 1/sqrt(128)

    float mx = sc;
#pragma unroll
    for (int o = 1; o < 16; o <<= 1) mx = fmaxf(mx, __shfl_xor(mx, o, 64));
    float e = __expf(sc - mx);
    float sm = e;
#pragma unroll
    for (int o = 1; o < 16; o <<= 1) sm += __shfl_xor(sm, o, 64);
    const float attn = e / sm;

    float o8[8] = {0.f, 0.f, 0.f, 0.f, 0.f, 0.f, 0.f, 0.f};
#pragma unroll
    for (int tt = 0; tt < 16; ++tt) {
        const float aw = __shfl(attn, (lane & 48) | tt, 64);
        const float* vp = &Vs[tt * LSTR + t * 8];
        float4 v0 = *(const float4*)(vp);
        float4 v1 = *(const float4*)(vp + 4);
        o8[0] += aw * v0.x; o8[1] += aw * v0.y; o8[2] += aw * v0.z; o8[3] += aw * v0.w;
        o8[4] += aw * v1.x; o8[5] += aw * v1.y; o8[6] += aw * v1.z; o8[7] += aw * v1.w;
    }

    const int orow = h * 256 + (s >> 4);
    const int ocol = (s & 15) * 128 + t * 8;
    float* op = out + ((size_t)b * S_ + orow) * DM_ + ocol;
    float4 w0 = { o8[0], o8[1], o8[2], o8[3] };
    float4 w1 = { o8[4], o8[5], o8[6], o8[7] };
    *(float4*)(op)     = w0;
    *(float4*)(op + 4) = w1;
}

// ---------------- launch ----------------
extern "C" void kernel_launch(void* const* d_in, const int* in_sizes, int n_in,
                              void* d_out, int out_size, void* d_ws, size_t ws_size,
                              hipStream_t stream) {
    const float* x  = (const float*)d_in[0];
    const float* Wq = (const float*)d_in[1];
    const float* bq = (const float*)d_in[2];
    const float* Wk = (const float*)d_in[3];
    const float* bk = (const float*)d_in[4];
    const float* Wv = (const float*)d_in[5];
    const float* bv = (const float*)d_in[6];
    float* out = (float*)d_out;

    char* ws = (char*)d_ws;
    unsigned short* xb  = (unsigned short*)ws;                       // 33,554,432 B
    unsigned short* Wb  = (unsigned short*)(ws + 33554432);          // 25,165,824 B
    unsigned short* qkv = (unsigned short*)(ws + 58720256);          // 100,663,296 B

    cast_all<<<2048, 256, 0, stream>>>(x, Wq, Wk, Wv, xb);           // xb + Wb contiguous

    gemm_qkv<<<(M_TOT / 256) * (N_TOT / 256), 512, 0, stream>>>(xb, Wb, bq, bk, bv, qkv);

    attn_kernel<<<M_TOT, 256, 0, stream>>>(qkv, out);
}